// Round 7
// baseline (463.156 us; speedup 1.0000x reference)
//
#include <hip/hip_runtime.h>

// DIAGNOSTIC + CANDIDATE ROUND.
// Order on stream: probe_mix (garbage) -> interior_copy (frame cols junk)
//                  -> border_kernel (patches every frame cell).
// Final writer of every out cell is correct; earlier garbage is overwritten.

typedef float f32x4 __attribute__((ext_vector_type(4)));
typedef float f32x2 __attribute__((ext_vector_type(2)));

// ---- probe: m13-style flat float4 copy, x (268 MB) -> out flat, 3 reps ----
__global__ __launch_bounds__(256) void probe_mix(const float* __restrict__ x,
                                                 float* __restrict__ out, int reps)
{
    const size_t N4 = 16777216;                    // 268 MB / 16 B
    for (int rep = 0; rep < reps; ++rep) {
        for (size_t i = blockIdx.x * 256 + threadIdx.x; i < N4;
             i += (size_t)gridDim.x * 256) {
            ((f32x4*)out)[i] = ((const f32x4*)x)[i];
        }
        asm volatile("" ::: "memory");
    }
}

// ---- production copy: per-slice, uniform, no LDS/barriers ----
// Writes 65 aligned float4 per interior row (probe_wpat store pattern);
// loads are the probe_rpat pattern. Frame cols 0,1,258,259 get junk here
// and are overwritten by border_kernel afterwards.
__global__ __launch_bounds__(512) void interior_copy(const float* __restrict__ x,
                                                     float* __restrict__ out)
{
    const int tid = threadIdx.x;
    const int bc  = blockIdx.x;
    const float* xs = x + (size_t)bc * 65536;
    float*       os = out + (size_t)bc * 67600;

    for (int idx = tid; idx < 256 * 65; idx += 512) {
        int r = idx / 65;
        int k = idx - r * 65;
        float*       orow = os + (size_t)(r + 2) * 260;
        const float* xrow = xs + (size_t)r * 256;
        f32x4 val;
        if (k == 0) {            // dst cols 0..3: {junk,junk,x0,x1}
            f32x2 a = *(const f32x2*)(xrow);
            val = (f32x4){a.x, a.y, a.x, a.y};
        } else if (k == 64) {    // dst cols 256..259: {x254,x255,junk,junk}
            f32x2 c = *(const f32x2*)(xrow + 254);
            val = (f32x4){c.x, c.y, c.x, c.y};
        } else {                 // dst cols 4k..4k+3 = x[4k-2..4k+1]
            f32x2 a = *(const f32x2*)(xrow + 4 * k - 2);
            f32x2 c = *(const f32x2*)(xrow + 4 * k);
            val = (f32x4){a.x, a.y, c.x, c.y};
        }
        *(f32x4*)(orow + 4 * k) = val;
    }
}

// ---- border: R1's proven kernel (SGPR weights, LDS 4-stage program) ----

__device__ __forceinline__ int bmap(int r) { return r < 4 ? r : r - 251; }

template <int S>
__device__ __forceinline__ float mlp6(const float* v,
                                      const float* __restrict__ w1, const float* __restrict__ b1,
                                      const float* __restrict__ w2, const float* __restrict__ b2,
                                      const float* __restrict__ w3, const float* __restrict__ b3)
{
    const float* __restrict__ W1 = w1 + S * 48;
    const float* __restrict__ B1 = b1 + S * 8;
    const float* __restrict__ W2 = w2 + S * 64;
    const float* __restrict__ B2 = b2 + S * 8;
    const float* __restrict__ W3 = w3 + S * 8;
    const float  b3s = b3[S];
    float h1[8];
#pragma unroll
    for (int h = 0; h < 8; ++h) {
        float a = B1[h];
#pragma unroll
        for (int q = 0; q < 6; ++q) a = fmaf(v[q], W1[h * 6 + q], a);
        h1[h] = fmaxf(a, 0.f);
    }
    float h2[8];
#pragma unroll
    for (int g = 0; g < 8; ++g) {
        float a = B2[g];
#pragma unroll
        for (int h = 0; h < 8; ++h) a = fmaf(h1[h], W2[g * 8 + h], a);
        h2[g] = fmaxf(a, 0.f);
    }
    float o = b3s;
#pragma unroll
    for (int g = 0; g < 8; ++g) o = fmaf(h2[g], W3[g], o);
    return fmaxf(o, 0.f);
}

template <int S>
__device__ __forceinline__ void hstage(int it, int tid,
                                       float (*rowS)[260], float (*colS)[260],
                                       const float* __restrict__ w1, const float* __restrict__ b1,
                                       const float* __restrict__ w2, const float* __restrict__ b2,
                                       const float* __restrict__ w3, const float* __restrict__ b3)
{
    int rin0, rin1, rout;
    if (S == 0) { rin0 = 2 - it;   rin1 = 3 - it;   rout = 1 - it;   }
    else        { rin0 = 255 + it; rin1 = 256 + it; rout = 258 + it; }
    const int a0 = bmap(rin0), a1 = bmap(rin1), ao = bmap(rout);
    for (int j0 = tid; j0 < 258; j0 += 256) {
        int j = j0 + 1;
        float v[6];
        v[0] = rowS[a0][j - 1]; v[1] = rowS[a0][j]; v[2] = rowS[a0][j + 1];
        v[3] = rowS[a1][j - 1]; v[4] = rowS[a1][j]; v[5] = rowS[a1][j + 1];
        float o = mlp6<S>(v, w1, b1, w2, b2, w3, b3);
        rowS[ao][j] = o;
        if (j < 4 || j >= 255) colS[bmap(j)][rout] = o;
    }
}

template <int S>
__device__ __forceinline__ void vstage(int it, int tid,
                                       float (*rowS)[260], float (*colS)[260],
                                       const float* __restrict__ w1, const float* __restrict__ b1,
                                       const float* __restrict__ w2, const float* __restrict__ b2,
                                       const float* __restrict__ w3, const float* __restrict__ b3)
{
    int cin0, cin1, cout;
    if (S == 2) { cin0 = 2 - it;   cin1 = 3 - it;   cout = 1 - it;   }
    else        { cin0 = 255 + it; cin1 = 256 + it; cout = 258 + it; }
    const int a0 = bmap(cin0), a1 = bmap(cin1), ao = bmap(cout);
    for (int r0 = tid; r0 < 258; r0 += 256) {
        int r = r0 + 1;
        float v[6];
        v[0] = colS[a0][r - 1]; v[1] = colS[a0][r]; v[2] = colS[a0][r + 1];
        v[3] = colS[a1][r - 1]; v[4] = colS[a1][r]; v[5] = colS[a1][r + 1];
        float o = mlp6<S>(v, w1, b1, w2, b2, w3, b3);
        colS[ao][r] = o;
        if (r < 4 || r >= 255) rowS[bmap(r)][cout] = o;
    }
}

__global__ __launch_bounds__(256) void border_kernel(
    const float* __restrict__ x,
    const float* __restrict__ w1, const float* __restrict__ b1,
    const float* __restrict__ w2, const float* __restrict__ b2,
    const float* __restrict__ w3, const float* __restrict__ b3,
    float* __restrict__ out)
{
    const int tid = threadIdx.x;
    const int bc  = blockIdx.x;
    const float* xs = x + (size_t)bc * 65536;
    float*       os = out + (size_t)bc * 67600;

    __shared__ float rowS[9][260];
    __shared__ float colS[9][260];

    for (int idx = tid; idx < 9 * 260; idx += 256) {
        (&rowS[0][0])[idx] = 0.f;
        (&colS[0][0])[idx] = 0.f;
    }
    __syncthreads();

    for (int which = 0; which < 5; ++which) {
        int xr = which < 2 ? which : 251 + which;   // 0,1,253,254,255
        rowS[2 + which][2 + tid] = xs[xr * 256 + tid];
        colS[2 + which][2 + tid] = xs[tid * 256 + xr];
    }
    __syncthreads();

    for (int it = 0; it < 2; ++it) {
        hstage<0>(it, tid, rowS, colS, w1, b1, w2, b2, w3, b3);
        hstage<1>(it, tid, rowS, colS, w1, b1, w2, b2, w3, b3);
        __syncthreads();
        vstage<2>(it, tid, rowS, colS, w1, b1, w2, b2, w3, b3);
        vstage<3>(it, tid, rowS, colS, w1, b1, w2, b2, w3, b3);
        __syncthreads();
    }

    // frame rows 0,1,258,259 full width (corners = 0 as in ref)
    for (int idx = tid; idx < 4 * 260; idx += 256) {
        int w = idx / 260, cc = idx % 260;
        int rr = w < 2 ? w : 256 + w;
        os[(size_t)rr * 260 + cc] = rowS[bmap(rr)][cc];
    }
    // col strips: cols 0,1 and 258,259 for rows 2..257 (overwrites copy junk)
    for (int idx = tid; idx < 2 * 256; idx += 256) {
        int w = idx >> 8;
        int r = (idx & 255) + 2;
        float* orow = os + (size_t)r * 260;
        if (w == 0) *(f32x2*)(orow)       = (f32x2){colS[0][r], colS[1][r]};
        else        *(f32x2*)(orow + 258) = (f32x2){colS[7][r], colS[8][r]};
    }
}

extern "C" void kernel_launch(void* const* d_in, const int* in_sizes, int n_in,
                              void* d_out, int out_size, void* d_ws, size_t ws_size,
                              hipStream_t stream)
{
    const float* x  = (const float*)d_in[0];
    const float* w1 = (const float*)d_in[1];
    const float* b1 = (const float*)d_in[2];
    const float* w2 = (const float*)d_in[3];
    const float* b2 = (const float*)d_in[4];
    const float* w3 = (const float*)d_in[5];
    const float* b3 = (const float*)d_in[6];
    float* out = (float*)d_out;

    probe_mix<<<2048, 256, 0, stream>>>(x, out, 3);          // diagnostic, garbage
    interior_copy<<<1024, 512, 0, stream>>>(x, out);          // frame cols junk
    border_kernel<<<1024, 256, 0, stream>>>(x, w1, b1, w2, b2, w3, b3, out);
}

// Round 8
// 177.924 us; speedup vs baseline: 2.6031x; 2.6031x over previous
//
#include <hip/hip_runtime.h>

// B=8, C=128, H=W=256, P=2, R=2, WP=3, HID=8. Output xp: (B,C,260,260) fp32.
// Single kernel, grid 1152 x 512:
//   blocks 0..127   : border role — each runs the full 4-stage border program
//                     for 8 slices sequentially (LDS, SGPR weights), writing
//                     frame rows 0,1,258,259 + col strips (cols 0,1/258,259).
//   blocks 128..1151: copy role — slice bid-128, stream xp[r+2][2..257] =
//                     x[r][0..255] (f32x2 + 63*f32x4 + f32x2 per row).
// Roles write DISJOINT cells -> no inter-block ordering needed. Border blocks
// are first in dispatch order so they are resident from t=0 and hide under
// the ~118 us BW-bound copy; their strided column gathers are diluted 8x
// vs R5 (128 concurrent gatherers, not 1024).

typedef float f32x4 __attribute__((ext_vector_type(4)));
typedef float f32x2 __attribute__((ext_vector_type(2)));

constexpr int NB = 128;                 // border blocks; each does 1024/NB slices

__device__ __forceinline__ int bmap(int r) { return r < 4 ? r : r - 251; }

template <int S>
__device__ __forceinline__ float mlp6(const float* v,
                                      const float* __restrict__ w1, const float* __restrict__ b1,
                                      const float* __restrict__ w2, const float* __restrict__ b2,
                                      const float* __restrict__ w3, const float* __restrict__ b3)
{
    const float* __restrict__ W1 = w1 + S * 48;  // [8][6]
    const float* __restrict__ B1 = b1 + S * 8;
    const float* __restrict__ W2 = w2 + S * 64;  // [8][8]
    const float* __restrict__ B2 = b2 + S * 8;
    const float* __restrict__ W3 = w3 + S * 8;
    const float  b3s = b3[S];

    float h1[8];
#pragma unroll
    for (int h = 0; h < 8; ++h) {
        float a = B1[h];
#pragma unroll
        for (int q = 0; q < 6; ++q) a = fmaf(v[q], W1[h * 6 + q], a);
        h1[h] = fmaxf(a, 0.f);
    }
    float h2[8];
#pragma unroll
    for (int g = 0; g < 8; ++g) {
        float a = B2[g];
#pragma unroll
        for (int h = 0; h < 8; ++h) a = fmaf(h1[h], W2[g * 8 + h], a);
        h2[g] = fmaxf(a, 0.f);
    }
    float o = b3s;
#pragma unroll
    for (int g = 0; g < 8; ++g) o = fmaf(h2[g], W3[g], o);
    return fmaxf(o, 0.f);
}

template <int S>
__device__ __forceinline__ void hstage(int it, int tid,
                                       float (*rowS)[260], float (*colS)[260],
                                       const float* __restrict__ w1, const float* __restrict__ b1,
                                       const float* __restrict__ w2, const float* __restrict__ b2,
                                       const float* __restrict__ w3, const float* __restrict__ b3)
{
    int rin0, rin1, rout;
    if (S == 0) { rin0 = 2 - it;   rin1 = 3 - it;   rout = 1 - it;   }
    else        { rin0 = 255 + it; rin1 = 256 + it; rout = 258 + it; }
    const int a0 = bmap(rin0), a1 = bmap(rin1), ao = bmap(rout);
    for (int j0 = tid; j0 < 258; j0 += 512) {
        int j = j0 + 1;
        float v[6];
        v[0] = rowS[a0][j - 1]; v[1] = rowS[a0][j]; v[2] = rowS[a0][j + 1];
        v[3] = rowS[a1][j - 1]; v[4] = rowS[a1][j]; v[5] = rowS[a1][j + 1];
        float o = mlp6<S>(v, w1, b1, w2, b2, w3, b3);
        rowS[ao][j] = o;
        if (j < 4 || j >= 255) colS[bmap(j)][rout] = o;  // keep col views consistent
    }
}

template <int S>
__device__ __forceinline__ void vstage(int it, int tid,
                                       float (*rowS)[260], float (*colS)[260],
                                       const float* __restrict__ w1, const float* __restrict__ b1,
                                       const float* __restrict__ w2, const float* __restrict__ b2,
                                       const float* __restrict__ w3, const float* __restrict__ b3)
{
    int cin0, cin1, cout;
    if (S == 2) { cin0 = 2 - it;   cin1 = 3 - it;   cout = 1 - it;   }
    else        { cin0 = 255 + it; cin1 = 256 + it; cout = 258 + it; }
    const int a0 = bmap(cin0), a1 = bmap(cin1), ao = bmap(cout);
    for (int r0 = tid; r0 < 258; r0 += 512) {
        int r = r0 + 1;
        float v[6];
        v[0] = colS[a0][r - 1]; v[1] = colS[a0][r]; v[2] = colS[a0][r + 1];
        v[3] = colS[a1][r - 1]; v[4] = colS[a1][r]; v[5] = colS[a1][r + 1];
        float o = mlp6<S>(v, w1, b1, w2, b2, w3, b3);
        colS[ao][r] = o;
        if (r < 4 || r >= 255) rowS[bmap(r)][cout] = o;  // keep row views consistent
    }
}

__device__ void border_slice(int bc, int tid,
                             const float* __restrict__ x,
                             const float* __restrict__ w1, const float* __restrict__ b1,
                             const float* __restrict__ w2, const float* __restrict__ b2,
                             const float* __restrict__ w3, const float* __restrict__ b3,
                             float* __restrict__ out,
                             float (*rowS)[260], float (*colS)[260])
{
    const float* xs = x + (size_t)bc * 65536;
    float*       os = out + (size_t)bc * 67600;

    __syncthreads();   // protect LDS reuse from previous slice's readers
    for (int idx = tid; idx < 9 * 260; idx += 512) {
        (&rowS[0][0])[idx] = 0.f;
        (&colS[0][0])[idx] = 0.f;
    }
    __syncthreads();

    // xp rows/cols 2,3,255,256,257 = x rows/cols 0,1,253,254,255
    for (int idx = tid; idx < 5 * 256; idx += 512) {
        int which = idx >> 8, t = idx & 255;
        int xr = which < 2 ? which : 251 + which;
        rowS[2 + which][2 + t] = xs[xr * 256 + t];
    }
    for (int idx = tid; idx < 5 * 256; idx += 512) {
        int which = idx >> 8, t = idx & 255;
        int xr = which < 2 ? which : 251 + which;
        colS[2 + which][2 + t] = xs[t * 256 + xr];   // strided gather (diluted)
    }
    __syncthreads();

    for (int it = 0; it < 2; ++it) {
        hstage<0>(it, tid, rowS, colS, w1, b1, w2, b2, w3, b3);
        hstage<1>(it, tid, rowS, colS, w1, b1, w2, b2, w3, b3);
        __syncthreads();
        vstage<2>(it, tid, rowS, colS, w1, b1, w2, b2, w3, b3);
        vstage<3>(it, tid, rowS, colS, w1, b1, w2, b2, w3, b3);
        __syncthreads();
    }

    // frame rows 0,1,258,259 full width (corners = 0, matching ref)
    for (int idx = tid; idx < 4 * 260; idx += 512) {
        int w = idx / 260, cc = idx % 260;
        int rr = w < 2 ? w : 256 + w;
        os[(size_t)rr * 260 + cc] = rowS[bmap(rr)][cc];
    }
    // col strips: cols 0,1 and 258,259 for rows 2..257
    for (int idx = tid; idx < 2 * 256; idx += 512) {
        int w = idx >> 8;
        int r = (idx & 255) + 2;
        float* orow = os + (size_t)r * 260;
        if (w == 0) *(f32x2*)(orow)       = (f32x2){colS[0][r], colS[1][r]};
        else        *(f32x2*)(orow + 258) = (f32x2){colS[7][r], colS[8][r]};
    }
}

__device__ void copy_slice(int bc, int tid,
                           const float* __restrict__ x, float* __restrict__ out)
{
    const float* xs = x + (size_t)bc * 65536;
    float*       os = out + (size_t)bc * 67600;
    for (int idx = tid; idx < 256 * 65; idx += 512) {
        int r = idx / 65;
        int k = idx - r * 65;
        float*       orow = os + (size_t)(r + 2) * 260;
        const float* xrow = xs + (size_t)r * 256;
        if (k == 0) {
            *(f32x2*)(orow + 2)   = *(const f32x2*)(xrow);          // cols 2,3
        } else if (k == 64) {
            *(f32x2*)(orow + 256) = *(const f32x2*)(xrow + 254);    // cols 256,257
        } else {
            f32x2 a = *(const f32x2*)(xrow + 4 * k - 2);
            f32x2 c = *(const f32x2*)(xrow + 4 * k);
            *(f32x4*)(orow + 4 * k) = (f32x4){a.x, a.y, c.x, c.y};  // cols 4k..4k+3
        }
    }
}

__global__ __launch_bounds__(512) void padding_fused(
    const float* __restrict__ x,
    const float* __restrict__ w1, const float* __restrict__ b1,
    const float* __restrict__ w2, const float* __restrict__ b2,
    const float* __restrict__ w3, const float* __restrict__ b3,
    float* __restrict__ out)
{
    __shared__ float rowS[9][260];
    __shared__ float colS[9][260];

    const int tid = threadIdx.x;
    const int bid = blockIdx.x;

    if (bid < NB) {
        // border role: slices bid, bid+NB, ... (1024/NB slices each)
        for (int s = bid; s < 1024; s += NB)
            border_slice(s, tid, x, w1, b1, w2, b2, w3, b3, out, rowS, colS);
    } else {
        copy_slice(bid - NB, tid, x, out);
    }
}

extern "C" void kernel_launch(void* const* d_in, const int* in_sizes, int n_in,
                              void* d_out, int out_size, void* d_ws, size_t ws_size,
                              hipStream_t stream)
{
    const float* x  = (const float*)d_in[0];
    const float* w1 = (const float*)d_in[1];
    const float* b1 = (const float*)d_in[2];
    const float* w2 = (const float*)d_in[3];
    const float* b2 = (const float*)d_in[4];
    const float* w3 = (const float*)d_in[5];
    const float* b3 = (const float*)d_in[6];
    float* out = (float*)d_out;

    padding_fused<<<1024 + NB, 512, 0, stream>>>(x, w1, b1, w2, b2, w3, b3, out);
}

// Round 9
// 165.486 us; speedup vs baseline: 2.7988x; 1.0752x over previous
//
#include <hip/hip_runtime.h>

// B=8, C=128, H=W=256, P=2, R=2, WP=3, HID=8. Output xp: (B,C,260,260) fp32.
// SEQUENTIAL two-kernel structure (overlap attempts R5/R8 both regressed):
//  K1 interior_copy_harvest: per-slice stream xp[r+2] rows as 65 aligned
//     float4 (frame cols get junk, patched by K2). While streaming, harvest
//     x cols {0,1,253,254,255} into ws[bc][5][256] (compact, col-major).
//  K2 border_ws: 4-stage border program per slice in LDS; row inputs read
//     coalesced from x, column inputs read COALESCED from ws. Writes frame
//     rows 0,1,258,259 + col strips (cols 0,1 / 258,259). No strided global
//     access anywhere.

typedef float f32x4 __attribute__((ext_vector_type(4)));
typedef float f32x2 __attribute__((ext_vector_type(2)));

constexpr size_t WS_NEED = (size_t)1024 * 5 * 256 * 4;   // 5.24 MB

__device__ __forceinline__ int bmap(int r) { return r < 4 ? r : r - 251; }

template <int S>
__device__ __forceinline__ float mlp6(const float* v,
                                      const float* __restrict__ w1, const float* __restrict__ b1,
                                      const float* __restrict__ w2, const float* __restrict__ b2,
                                      const float* __restrict__ w3, const float* __restrict__ b3)
{
    const float* __restrict__ W1 = w1 + S * 48;  // [8][6]
    const float* __restrict__ B1 = b1 + S * 8;
    const float* __restrict__ W2 = w2 + S * 64;  // [8][8]
    const float* __restrict__ B2 = b2 + S * 8;
    const float* __restrict__ W3 = w3 + S * 8;
    const float  b3s = b3[S];

    float h1[8];
#pragma unroll
    for (int h = 0; h < 8; ++h) {
        float a = B1[h];
#pragma unroll
        for (int q = 0; q < 6; ++q) a = fmaf(v[q], W1[h * 6 + q], a);
        h1[h] = fmaxf(a, 0.f);
    }
    float h2[8];
#pragma unroll
    for (int g = 0; g < 8; ++g) {
        float a = B2[g];
#pragma unroll
        for (int h = 0; h < 8; ++h) a = fmaf(h1[h], W2[g * 8 + h], a);
        h2[g] = fmaxf(a, 0.f);
    }
    float o = b3s;
#pragma unroll
    for (int g = 0; g < 8; ++g) o = fmaf(h2[g], W3[g], o);
    return fmaxf(o, 0.f);
}

template <int S>
__device__ __forceinline__ void hstage(int it, int tid,
                                       float (*rowS)[260], float (*colS)[260],
                                       const float* __restrict__ w1, const float* __restrict__ b1,
                                       const float* __restrict__ w2, const float* __restrict__ b2,
                                       const float* __restrict__ w3, const float* __restrict__ b3)
{
    int rin0, rin1, rout;
    if (S == 0) { rin0 = 2 - it;   rin1 = 3 - it;   rout = 1 - it;   }
    else        { rin0 = 255 + it; rin1 = 256 + it; rout = 258 + it; }
    const int a0 = bmap(rin0), a1 = bmap(rin1), ao = bmap(rout);
    for (int j0 = tid; j0 < 258; j0 += 256) {
        int j = j0 + 1;
        float v[6];
        v[0] = rowS[a0][j - 1]; v[1] = rowS[a0][j]; v[2] = rowS[a0][j + 1];
        v[3] = rowS[a1][j - 1]; v[4] = rowS[a1][j]; v[5] = rowS[a1][j + 1];
        float o = mlp6<S>(v, w1, b1, w2, b2, w3, b3);
        rowS[ao][j] = o;
        if (j < 4 || j >= 255) colS[bmap(j)][rout] = o;  // keep col views consistent
    }
}

template <int S>
__device__ __forceinline__ void vstage(int it, int tid,
                                       float (*rowS)[260], float (*colS)[260],
                                       const float* __restrict__ w1, const float* __restrict__ b1,
                                       const float* __restrict__ w2, const float* __restrict__ b2,
                                       const float* __restrict__ w3, const float* __restrict__ b3)
{
    int cin0, cin1, cout;
    if (S == 2) { cin0 = 2 - it;   cin1 = 3 - it;   cout = 1 - it;   }
    else        { cin0 = 255 + it; cin1 = 256 + it; cout = 258 + it; }
    const int a0 = bmap(cin0), a1 = bmap(cin1), ao = bmap(cout);
    for (int r0 = tid; r0 < 258; r0 += 256) {
        int r = r0 + 1;
        float v[6];
        v[0] = colS[a0][r - 1]; v[1] = colS[a0][r]; v[2] = colS[a0][r + 1];
        v[3] = colS[a1][r - 1]; v[4] = colS[a1][r]; v[5] = colS[a1][r + 1];
        float o = mlp6<S>(v, w1, b1, w2, b2, w3, b3);
        colS[ao][r] = o;
        if (r < 4 || r >= 255) rowS[bmap(r)][cout] = o;  // keep row views consistent
    }
}

// ---- K1: interior stream (65 aligned float4/row) + edge-column harvest ----
__global__ __launch_bounds__(512) void interior_copy_harvest(
    const float* __restrict__ x, float* __restrict__ out, float* __restrict__ ws)
{
    const int tid = threadIdx.x;
    const int bc  = blockIdx.x;
    const float* xs = x + (size_t)bc * 65536;
    float*       os = out + (size_t)bc * 67600;
    float*       wsl = ws + (size_t)bc * 1280;     // [5][256]

    for (int idx = tid; idx < 256 * 65; idx += 512) {
        int r = idx / 65;
        int k = idx - r * 65;
        float*       orow = os + (size_t)(r + 2) * 260;
        const float* xrow = xs + (size_t)r * 256;
        f32x4 val;
        if (k == 0) {            // dst cols 0..3: {junk,junk,x0,x1}
            f32x2 a = *(const f32x2*)(xrow);
            val = (f32x4){a.x, a.y, a.x, a.y};
            wsl[r]       = a.x;                    // x col 0
            wsl[256 + r] = a.y;                    // x col 1
        } else if (k == 63) {    // dst cols 252..255 = x cols 250..253
            f32x2 a = *(const f32x2*)(xrow + 250);
            f32x2 c = *(const f32x2*)(xrow + 252);
            val = (f32x4){a.x, a.y, c.x, c.y};
            wsl[512 + r] = c.y;                    // x col 253
        } else if (k == 64) {    // dst cols 256..259: {x254,x255,junk,junk}
            f32x2 c = *(const f32x2*)(xrow + 254);
            val = (f32x4){c.x, c.y, c.x, c.y};
            wsl[768 + r]  = c.x;                   // x col 254
            wsl[1024 + r] = c.y;                   // x col 255
        } else {                 // dst cols 4k..4k+3 = x[4k-2..4k+1]
            f32x2 a = *(const f32x2*)(xrow + 4 * k - 2);
            f32x2 c = *(const f32x2*)(xrow + 4 * k);
            val = (f32x4){a.x, a.y, c.x, c.y};
        }
        *(f32x4*)(orow + 4 * k) = val;
    }
}

// ---- K2: border program; columns from ws (coalesced) ----
template <bool USE_WS>
__global__ __launch_bounds__(256) void border_kernel(
    const float* __restrict__ x, const float* __restrict__ ws,
    const float* __restrict__ w1, const float* __restrict__ b1,
    const float* __restrict__ w2, const float* __restrict__ b2,
    const float* __restrict__ w3, const float* __restrict__ b3,
    float* __restrict__ out)
{
    const int tid = threadIdx.x;
    const int bc  = blockIdx.x;
    const float* xs = x + (size_t)bc * 65536;
    float*       os = out + (size_t)bc * 67600;

    __shared__ float rowS[9][260];
    __shared__ float colS[9][260];

    for (int idx = tid; idx < 9 * 260; idx += 256) {
        (&rowS[0][0])[idx] = 0.f;
        (&colS[0][0])[idx] = 0.f;
    }
    __syncthreads();

    // rows: coalesced from x. cols: coalesced from ws (or strided fallback).
    for (int which = 0; which < 5; ++which) {
        int xr = which < 2 ? which : 251 + which;   // 0,1,253,254,255
        rowS[2 + which][2 + tid] = xs[xr * 256 + tid];
        if (USE_WS) colS[2 + which][2 + tid] = ws[(size_t)bc * 1280 + which * 256 + tid];
        else        colS[2 + which][2 + tid] = xs[tid * 256 + xr];
    }
    __syncthreads();

    for (int it = 0; it < 2; ++it) {
        hstage<0>(it, tid, rowS, colS, w1, b1, w2, b2, w3, b3);
        hstage<1>(it, tid, rowS, colS, w1, b1, w2, b2, w3, b3);
        __syncthreads();
        vstage<2>(it, tid, rowS, colS, w1, b1, w2, b2, w3, b3);
        vstage<3>(it, tid, rowS, colS, w1, b1, w2, b2, w3, b3);
        __syncthreads();
    }

    // frame rows 0,1,258,259 full width (corners = 0 as in ref)
    for (int idx = tid; idx < 4 * 260; idx += 256) {
        int w = idx / 260, cc = idx % 260;
        int rr = w < 2 ? w : 256 + w;
        os[(size_t)rr * 260 + cc] = rowS[bmap(rr)][cc];
    }
    // col strips: cols 0,1 and 258,259 for rows 2..257 (overwrites copy junk)
    for (int idx = tid; idx < 2 * 256; idx += 256) {
        int w = idx >> 8;
        int r = (idx & 255) + 2;
        float* orow = os + (size_t)r * 260;
        if (w == 0) *(f32x2*)(orow)       = (f32x2){colS[0][r], colS[1][r]};
        else        *(f32x2*)(orow + 258) = (f32x2){colS[7][r], colS[8][r]};
    }
}

extern "C" void kernel_launch(void* const* d_in, const int* in_sizes, int n_in,
                              void* d_out, int out_size, void* d_ws, size_t ws_size,
                              hipStream_t stream)
{
    const float* x  = (const float*)d_in[0];
    const float* w1 = (const float*)d_in[1];
    const float* b1 = (const float*)d_in[2];
    const float* w2 = (const float*)d_in[3];
    const float* b2 = (const float*)d_in[4];
    const float* w3 = (const float*)d_in[5];
    const float* b3 = (const float*)d_in[6];
    float* out = (float*)d_out;
    float* ws  = (float*)d_ws;

    if (ws_size >= WS_NEED) {
        interior_copy_harvest<<<1024, 512, 0, stream>>>(x, out, ws);
        border_kernel<true><<<1024, 256, 0, stream>>>(x, ws, w1, b1, w2, b2, w3, b3, out);
    } else {
        interior_copy_harvest<<<1024, 512, 0, stream>>>(x, out, ws ? ws : out); // harvest dropped
        border_kernel<false><<<1024, 256, 0, stream>>>(x, ws, w1, b1, w2, b2, w3, b3, out);
    }
}